// Round 5
// baseline (530.453 us; speedup 1.0000x reference)
//
#include <hip/hip_runtime.h>
#include <stdint.h>

typedef short bf16x8 __attribute__((ext_vector_type(8)));
typedef float f32x4 __attribute__((ext_vector_type(4)));

#if __has_builtin(__builtin_amdgcn_exp2f)
#define EXP2F(x) __builtin_amdgcn_exp2f(x)
#else
#define EXP2F(x) exp2f(x)
#endif

// 0.125 (1/sqrt(64)) * log2(e): folded into Q so QK^T scores come out in
// log2 domain directly (softmax uses native v_exp_f32 = exp2).
#define QSCALE 0.18033688011112042f

__device__ __forceinline__ unsigned short f2bf(float f) {
  unsigned u = __float_as_uint(f);
  u += 0x7fffu + ((u >> 16) & 1u);
  return (unsigned short)(u >> 16);
}

// async global->LDS, 16B per lane; LDS dest = waveBase + lane*16 (call sites
// pass &buf[t*8], t = wid*64+lane -> consistent).
__device__ __forceinline__ void gld16(const ushort* g, ushort* l) {
  __builtin_amdgcn_global_load_lds(
      (__attribute__((address_space(1))) void*)g,
      (__attribute__((address_space(3))) void*)l, 16, 0, 0);
}

// ---------------- prep kernels ----------------
__global__ __launch_bounds__(256) void k_cast_bf16(const float* __restrict__ in,
                                                   ushort* __restrict__ out) {
  int i = (blockIdx.x * 256 + threadIdx.x) * 8;
  float4 a = *(const float4*)(in + i);
  float4 b = *(const float4*)(in + i + 4);
  union { ushort u[8]; uint4 q; } r;
  r.u[0] = f2bf(a.x); r.u[1] = f2bf(a.y); r.u[2] = f2bf(a.z); r.u[3] = f2bf(a.w);
  r.u[4] = f2bf(b.x); r.u[5] = f2bf(b.y); r.u[6] = f2bf(b.z); r.u[7] = f2bf(b.w);
  *(uint4*)(out + i) = r.q;
}

// fp32 [R][C] -> bf16 [C][R]
__global__ __launch_bounds__(256) void k_transpose_cast(const float* __restrict__ in,
                                                        ushort* __restrict__ out,
                                                        int R, int C) {
  __shared__ float tl[32][33];
  int t = threadIdx.x;
  {
    int r = t >> 3, c4 = (t & 7) * 4;
    float4 v = *(const float4*)(in + (size_t)(blockIdx.y * 32 + r) * C + blockIdx.x * 32 + c4);
    tl[r][c4] = v.x; tl[r][c4 + 1] = v.y; tl[r][c4 + 2] = v.z; tl[r][c4 + 3] = v.w;
  }
  __syncthreads();
  {
    int c = t >> 3, r4 = (t & 7) * 4;
    union { ushort u[4]; uint2 q; } o;
    o.u[0] = f2bf(tl[r4][c]);     o.u[1] = f2bf(tl[r4 + 1][c]);
    o.u[2] = f2bf(tl[r4 + 2][c]); o.u[3] = f2bf(tl[r4 + 3][c]);
    *(uint2*)(out + (size_t)(blockIdx.x * 32 + c) * R + blockIdx.y * 32 + r4) = o.q;
  }
}

// V [bh][2048][64] -> Vt [bh][64][2048]
__global__ __launch_bounds__(256) void k_vtrans(const ushort* __restrict__ V,
                                                ushort* __restrict__ Vt) {
  __shared__ ushort tl[64 * 72];
  int t = threadIdx.x;
  const ushort* inp = V + (size_t)blockIdx.y * 131072 + blockIdx.x * 4096;
#pragma unroll
  for (int p = 0; p < 2; ++p) {
    int r = (t >> 3) + p * 32, c8 = (t & 7) * 8;
    *(uint4*)&tl[r * 72 + c8] = *(const uint4*)&inp[r * 64 + c8];
  }
  __syncthreads();
  ushort* outp = Vt + (size_t)blockIdx.y * 131072 + blockIdx.x * 64;
#pragma unroll
  for (int p = 0; p < 2; ++p) {
    int d = (t >> 3) + p * 32, s8 = (t & 7) * 8;
    union { ushort u[8]; uint4 q; } o;
#pragma unroll
    for (int j = 0; j < 8; ++j) o.u[j] = tl[(s8 + j) * 72 + d];
    *(uint4*)&outp[d * 2048 + s8] = o.q;
  }
}

// ---------------- GEMM: A[M][1024] bf16 x Bt[N][1024] bf16 ----------------
// m97-verified pattern: LINEAR LDS (no swizzle) + global_load_lds width 16.
// 128x128 tile, BK=32, 4 waves (2x2), each wave 64x64 (4x4 of 16x16 frags).
// MODE 0 epilogue scales the Q third by QSCALE (log2-domain softmax).
template <int MODE>
__global__ __launch_bounds__(256, 2) void k_gemm(
    const ushort* __restrict__ A, const ushort* __restrict__ Bt,
    const float* __restrict__ bias, ushort* __restrict__ Q,
    ushort* __restrict__ Ko, ushort* __restrict__ V, float* __restrict__ Out) {
  __shared__ ushort As[128 * 32];
  __shared__ ushort Bs[128 * 32];
  const int t = threadIdx.x;
  const int lane = t & 63, wid = t >> 6;
  const int wr = wid >> 1, wc = wid & 1;
  const int rt = blockIdx.y, ct = blockIdx.x;

  const int srow = t >> 2, sslot = t & 3;
  const ushort* ga = A + (size_t)(rt * 128 + srow) * 1024 + sslot * 8;
  const ushort* gb = Bt + (size_t)(ct * 128 + srow) * 1024 + sslot * 8;
  ushort* lA = &As[t * 8];
  ushort* lB = &Bs[t * 8];

  f32x4 acc[4][4];
#pragma unroll
  for (int m = 0; m < 4; ++m)
#pragma unroll
    for (int n = 0; n < 4; ++n) acc[m][n] = (f32x4){0.f, 0.f, 0.f, 0.f};

  int aidx[4], bidx[4];
#pragma unroll
  for (int m = 0; m < 4; ++m) {
    int ra = wr * 64 + m * 16 + (lane & 15);
    aidx[m] = ra * 32 + ((lane >> 4) << 3);
    int rb = wc * 64 + m * 16 + (lane & 15);
    bidx[m] = rb * 32 + ((lane >> 4) << 3);
  }

  gld16(ga, lA); gld16(ga + 65536, lA + 2048);
  gld16(gb, lB); gld16(gb + 65536, lB + 2048);

  for (int kt = 0; kt < 32; ++kt) {
    __syncthreads();
    bf16x8 af[4], bfv[4];
#pragma unroll
    for (int m = 0; m < 4; ++m) af[m] = *(const bf16x8*)&As[aidx[m]];
#pragma unroll
    for (int n = 0; n < 4; ++n) bfv[n] = *(const bf16x8*)&Bs[bidx[n]];
    __syncthreads();
    if (kt < 31) {
      const ushort* ga2 = ga + (kt + 1) * 32;
      const ushort* gb2 = gb + (kt + 1) * 32;
      gld16(ga2, lA); gld16(ga2 + 65536, lA + 2048);
      gld16(gb2, lB); gld16(gb2 + 65536, lB + 2048);
    }
#pragma unroll
    for (int m = 0; m < 4; ++m)
#pragma unroll
      for (int n = 0; n < 4; ++n)
        acc[m][n] = __builtin_amdgcn_mfma_f32_16x16x32_bf16(af[m], bfv[n], acc[m][n], 0, 0, 0);
  }

  const int colb = ct * 128 + wc * 64;
  const int rowb = rt * 128 + wr * 64;
  if constexpr (MODE == 0) {
#pragma unroll
    for (int n = 0; n < 4; ++n) {
      int col = colb + n * 16 + (lane & 15);
      float bv = bias[col];
      int three = col >> 10, hx = (col >> 6) & 15, d = col & 63;
      float sc = (three == 0) ? QSCALE : 1.0f;
      ushort* dst = (three == 0) ? Q : (three == 1) ? Ko : V;
#pragma unroll
      for (int m = 0; m < 4; ++m) {
        int r0 = rowb + m * 16 + ((lane >> 4) << 2);
#pragma unroll
        for (int r = 0; r < 4; ++r) {
          int row = r0 + r;
          int b = row >> 11, s = row & 2047;
          dst[(size_t)((b * 16 + hx) * 2048 + s) * 64 + d] = f2bf((acc[m][n][r] + bv) * sc);
        }
      }
    }
  } else {
#pragma unroll
    for (int n = 0; n < 4; ++n) {
      int col = colb + n * 16 + (lane & 15);
      float bv = bias[col];
#pragma unroll
      for (int m = 0; m < 4; ++m) {
        int r0 = rowb + m * 16 + ((lane >> 4) << 2);
#pragma unroll
        for (int r = 0; r < 4; ++r)
          Out[(size_t)(r0 + r) * 1024 + col] = acc[m][n][r] + bv;
      }
    }
  }
}

// ---------------- flash attention ----------------
// grid (16 q-tiles, 32 bh) = 512 blocks. 512 threads / 8 waves, QBLK=128
// (16 q rows per wave). Staging per block-tile same as the r2 best (64x64
// K + V, each thread 16B+16B) but now amortized over 2x the MFMA work, and
// 2 blocks/CU x 8 waves = 16 waves/CU give cross-block overlap.
// K [64][72] / Vt [64][72] reg-staged (+8 pad, conflict-free). P in
// XOR-swizzled [128][64] LDS, wave-private 16-row stripes. Softmax in log2
// domain, per-lane deferred sum, defer-max rescale skip.
// __launch_bounds__(512,4): caps VGPR at 128 (live set ~90, no spill; r3's
// 64-cap spilled). 2 blocks/CU resident by VGPR.
__global__ __launch_bounds__(512, 4) void k_attn(const ushort* __restrict__ Qb,
                                                 const ushort* __restrict__ Kb,
                                                 const ushort* __restrict__ Vtb,
                                                 ushort* __restrict__ AO) {
  __shared__ ushort Ks[64 * 72];
  __shared__ ushort Vs[64 * 72];
  __shared__ ushort Ps[128 * 64];
  const int t = threadIdx.x, lane = t & 63, wid = t >> 6;  // wid 0..7
  const int c = lane & 15, g = lane >> 4;
  const int bh = blockIdx.y, qt = blockIdx.x;
  const ushort* Qh = Qb + (size_t)bh * 131072;
  const ushort* Kh = Kb + (size_t)bh * 131072;
  const ushort* Vh = Vtb + (size_t)bh * 131072;

  bf16x8 qf[2];
#pragma unroll
  for (int kk = 0; kk < 2; ++kk) {
    int row = qt * 128 + wid * 16 + c;
    qf[kk] = *(const bf16x8*)&Qh[row * 64 + kk * 32 + g * 8];
  }

  f32x4 oacc[4];
  float mrow[4], lpart[4];
#pragma unroll
  for (int n = 0; n < 4; ++n) oacc[n] = (f32x4){0.f, 0.f, 0.f, 0.f};
#pragma unroll
  for (int r = 0; r < 4; ++r) { mrow[r] = -1e30f; lpart[r] = 0.f; }

  // staging: 512 threads x 16B = one 64x64 bf16 tile each for K and V
  const int strow = t >> 3, stcol = (t & 7) * 8;

  int kidx[4][2];
#pragma unroll
  for (int n = 0; n < 4; ++n)
#pragma unroll
    for (int kk = 0; kk < 2; ++kk)
      kidx[n][kk] = (n * 16 + c) * 72 + (kk * 4 + g) * 8;

  // P-store geometry: q = wid*16 + g*4 + r; addr = q*64 + ((n*16)^(g<<4)) + c
  const int g16 = g << 4;
  int woff[4];
#pragma unroll
  for (int n = 0; n < 4; ++n) woff[n] = ((n * 16) ^ g16) + c;
  const int qbase = (wid * 16 + g * 4) * 64;
  // P-read: row = wid*16 + c, key = (row>>2)&3 = c>>2
  int pridx[2];
#pragma unroll
  for (int kk = 0; kk < 2; ++kk)
    pridx[kk] = (wid * 16 + c) * 64 + ((kk * 32 + g * 8) ^ ((c >> 2) << 4));

  uint4 kreg, vreg;
  kreg = *(const uint4*)&Kh[(size_t)strow * 64 + stcol];
  vreg = *(const uint4*)&Vh[(size_t)strow * 2048 + stcol];

  for (int kt = 0; kt < 32; ++kt) {
    __syncthreads();  // prev tile's reads done
    *(uint4*)&Ks[strow * 72 + stcol] = kreg;
    *(uint4*)&Vs[strow * 72 + stcol] = vreg;
    __syncthreads();  // tiles ready
    if (kt < 31) {    // overlap next-tile loads with compute
      kreg = *(const uint4*)&Kh[(size_t)((kt + 1) * 64 + strow) * 64 + stcol];
      vreg = *(const uint4*)&Vh[(size_t)strow * 2048 + (kt + 1) * 64 + stcol];
    }
    // QK^T (scores already in log2 domain via Q pre-scale)
    f32x4 sacc[4];
#pragma unroll
    for (int n = 0; n < 4; ++n) sacc[n] = (f32x4){0.f, 0.f, 0.f, 0.f};
#pragma unroll
    for (int kk = 0; kk < 2; ++kk)
#pragma unroll
      for (int n = 0; n < 4; ++n) {
        bf16x8 kf = *(const bf16x8*)&Ks[kidx[n][kk]];
        sacc[n] = __builtin_amdgcn_mfma_f32_16x16x32_bf16(qf[kk], kf, sacc[n], 0, 0, 0);
      }
    // online softmax, defer-max (THR=12 in log2), per-lane deferred sum
#pragma unroll
    for (int r = 0; r < 4; ++r) {
      float s0 = sacc[0][r], s1 = sacc[1][r], s2 = sacc[2][r], s3 = sacc[3][r];
      float mx = fmaxf(fmaxf(s0, s1), fmaxf(s2, s3));
#pragma unroll
      for (int off = 1; off < 16; off <<= 1) mx = fmaxf(mx, __shfl_xor(mx, off));
      float mo = mrow[r];
      float p0, p1, p2, p3;
      if (__all(mx <= mo + 12.0f)) {
        p0 = EXP2F(s0 - mo); p1 = EXP2F(s1 - mo);
        p2 = EXP2F(s2 - mo); p3 = EXP2F(s3 - mo);
        lpart[r] += (p0 + p1) + (p2 + p3);
      } else {
        float mn = fmaxf(mo, mx);
        float corr = EXP2F(mo - mn);
        mrow[r] = mn;
        p0 = EXP2F(s0 - mn); p1 = EXP2F(s1 - mn);
        p2 = EXP2F(s2 - mn); p3 = EXP2F(s3 - mn);
        lpart[r] = lpart[r] * corr + ((p0 + p1) + (p2 + p3));
        oacc[0][r] *= corr; oacc[1][r] *= corr;
        oacc[2][r] *= corr; oacc[3][r] *= corr;
      }
      int pb = qbase + r * 64;
      Ps[pb + woff[0]] = f2bf(p0); Ps[pb + woff[1]] = f2bf(p1);
      Ps[pb + woff[2]] = f2bf(p2); Ps[pb + woff[3]] = f2bf(p3);
    }
    // PV (P stripe is wave-private; same-wave ds ordering -> no barrier)
#pragma unroll
    for (int kk = 0; kk < 2; ++kk) {
      bf16x8 pa = *(const bf16x8*)&Ps[pridx[kk]];
#pragma unroll
      for (int nd = 0; nd < 4; ++nd) {
        bf16x8 vf = *(const bf16x8*)&Vs[kidx[nd][kk]];
        oacc[nd] = __builtin_amdgcn_mfma_f32_16x16x32_bf16(pa, vf, oacc[nd], 0, 0, 0);
      }
    }
  }

  const int b = bh >> 4, h = bh & 15;
  float inv[4];
#pragma unroll
  for (int r = 0; r < 4; ++r) {
#pragma unroll
    for (int off = 1; off < 16; off <<= 1) lpart[r] += __shfl_xor(lpart[r], off);
    inv[r] = 1.0f / lpart[r];
  }
#pragma unroll
  for (int nd = 0; nd < 4; ++nd) {
    int d = nd * 16 + c;
#pragma unroll
    for (int r = 0; r < 4; ++r) {
      int s = qt * 128 + wid * 16 + g * 4 + r;
      AO[(size_t)((b * 2048 + s) * 16 + h) * 64 + d] = f2bf(oacc[nd][r] * inv[r]);
    }
  }
}

extern "C" void kernel_launch(void* const* d_in, const int* in_sizes, int n_in,
                              void* d_out, int out_size, void* d_ws, size_t ws_size,
                              hipStream_t stream) {
  const float* x = (const float*)d_in[0];
  const float* w_qkv = (const float*)d_in[1];
  const float* b_qkv = (const float*)d_in[2];
  const float* w_out = (const float*)d_in[3];
  const float* b_out = (const float*)d_in[4];
  float* out = (float*)d_out;

  char* p = (char*)d_ws;
  ushort* xb = (ushort*)p;    p += (size_t)4096 * 1024 * 2;   // reused as AO later
  ushort* wqkvT = (ushort*)p; p += (size_t)3072 * 1024 * 2;
  ushort* woutT = (ushort*)p; p += (size_t)1024 * 1024 * 2;
  ushort* Qb = (ushort*)p;    p += (size_t)32 * 2048 * 64 * 2;
  ushort* Kb = (ushort*)p;    p += (size_t)32 * 2048 * 64 * 2;
  ushort* Vb = (ushort*)p;    p += (size_t)32 * 2048 * 64 * 2;
  ushort* Vtb = (ushort*)p;   p += (size_t)32 * 2048 * 64 * 2;
  ushort* AO = xb;  // xb dead after QKV GEMM; reuse (stream-ordered, safe)

  k_cast_bf16<<<2048, 256, 0, stream>>>(x, xb);
  k_transpose_cast<<<dim3(96, 32), 256, 0, stream>>>(w_qkv, wqkvT, 1024, 3072);
  k_transpose_cast<<<dim3(32, 32), 256, 0, stream>>>(w_out, woutT, 1024, 1024);
  k_gemm<0><<<dim3(24, 32), 256, 0, stream>>>(xb, wqkvT, b_qkv, Qb, Kb, Vb, nullptr);
  k_vtrans<<<dim3(32, 32), 256, 0, stream>>>(Vb, Vtb);
  k_attn<<<dim3(16, 32), 512, 0, stream>>>(Qb, Kb, Vtb, AO);
  k_gemm<1><<<dim3(8, 32), 256, 0, stream>>>(AO, woutT, b_out, nullptr, nullptr, nullptr, out);
}

// Round 6
// 205.624 us; speedup vs baseline: 2.5797x; 2.5797x over previous
//
#include <hip/hip_runtime.h>
#include <stdint.h>

typedef short bf16x8 __attribute__((ext_vector_type(8)));
typedef float f32x4 __attribute__((ext_vector_type(4)));

#if __has_builtin(__builtin_amdgcn_exp2f)
#define EXP2F(x) __builtin_amdgcn_exp2f(x)
#else
#define EXP2F(x) exp2f(x)
#endif

// 0.125 (1/sqrt(64)) * log2(e): folded into Q so QK^T scores come out in
// log2 domain directly (softmax uses native v_exp_f32 = exp2).
#define QSCALE 0.18033688011112042f

__device__ __forceinline__ unsigned short f2bf(float f) {
  unsigned u = __float_as_uint(f);
  u += 0x7fffu + ((u >> 16) & 1u);
  return (unsigned short)(u >> 16);
}

// async global->LDS, 16B per lane; LDS dest = waveBase + lane*16 (call sites
// pass &buf[t*8], t = wid*64+lane -> consistent).
__device__ __forceinline__ void gld16(const ushort* g, ushort* l) {
  __builtin_amdgcn_global_load_lds(
      (__attribute__((address_space(1))) void*)g,
      (__attribute__((address_space(3))) void*)l, 16, 0, 0);
}

// ---------------- prep kernels ----------------
__global__ __launch_bounds__(256) void k_cast_bf16(const float* __restrict__ in,
                                                   ushort* __restrict__ out) {
  int i = (blockIdx.x * 256 + threadIdx.x) * 8;
  float4 a = *(const float4*)(in + i);
  float4 b = *(const float4*)(in + i + 4);
  union { ushort u[8]; uint4 q; } r;
  r.u[0] = f2bf(a.x); r.u[1] = f2bf(a.y); r.u[2] = f2bf(a.z); r.u[3] = f2bf(a.w);
  r.u[4] = f2bf(b.x); r.u[5] = f2bf(b.y); r.u[6] = f2bf(b.z); r.u[7] = f2bf(b.w);
  *(uint4*)(out + i) = r.q;
}

// fp32 [R][C] -> bf16 [C][R]
__global__ __launch_bounds__(256) void k_transpose_cast(const float* __restrict__ in,
                                                        ushort* __restrict__ out,
                                                        int R, int C) {
  __shared__ float tl[32][33];
  int t = threadIdx.x;
  {
    int r = t >> 3, c4 = (t & 7) * 4;
    float4 v = *(const float4*)(in + (size_t)(blockIdx.y * 32 + r) * C + blockIdx.x * 32 + c4);
    tl[r][c4] = v.x; tl[r][c4 + 1] = v.y; tl[r][c4 + 2] = v.z; tl[r][c4 + 3] = v.w;
  }
  __syncthreads();
  {
    int c = t >> 3, r4 = (t & 7) * 4;
    union { ushort u[4]; uint2 q; } o;
    o.u[0] = f2bf(tl[r4][c]);     o.u[1] = f2bf(tl[r4 + 1][c]);
    o.u[2] = f2bf(tl[r4 + 2][c]); o.u[3] = f2bf(tl[r4 + 3][c]);
    *(uint2*)(out + (size_t)(blockIdx.x * 32 + c) * R + blockIdx.y * 32 + r4) = o.q;
  }
}

// V [bh][2048][64] -> Vt [bh][64][2048]
__global__ __launch_bounds__(256) void k_vtrans(const ushort* __restrict__ V,
                                                ushort* __restrict__ Vt) {
  __shared__ ushort tl[64 * 72];
  int t = threadIdx.x;
  const ushort* inp = V + (size_t)blockIdx.y * 131072 + blockIdx.x * 4096;
#pragma unroll
  for (int p = 0; p < 2; ++p) {
    int r = (t >> 3) + p * 32, c8 = (t & 7) * 8;
    *(uint4*)&tl[r * 72 + c8] = *(const uint4*)&inp[r * 64 + c8];
  }
  __syncthreads();
  ushort* outp = Vt + (size_t)blockIdx.y * 131072 + blockIdx.x * 64;
#pragma unroll
  for (int p = 0; p < 2; ++p) {
    int d = (t >> 3) + p * 32, s8 = (t & 7) * 8;
    union { ushort u[8]; uint4 q; } o;
#pragma unroll
    for (int j = 0; j < 8; ++j) o.u[j] = tl[(s8 + j) * 72 + d];
    *(uint4*)&outp[d * 2048 + s8] = o.q;
  }
}

// ---------------- GEMM: A[M][1024] bf16 x Bt[N][1024] bf16 ----------------
// m97-verified pattern: LINEAR LDS (no swizzle) + global_load_lds width 16.
// 128x128 tile, BK=32, 4 waves (2x2), each wave 64x64 (4x4 of 16x16 frags).
// MODE 0 epilogue scales the Q third by QSCALE (log2-domain softmax).
template <int MODE>
__global__ __launch_bounds__(256, 2) void k_gemm(
    const ushort* __restrict__ A, const ushort* __restrict__ Bt,
    const float* __restrict__ bias, ushort* __restrict__ Q,
    ushort* __restrict__ Ko, ushort* __restrict__ V, float* __restrict__ Out) {
  __shared__ ushort As[128 * 32];
  __shared__ ushort Bs[128 * 32];
  const int t = threadIdx.x;
  const int lane = t & 63, wid = t >> 6;
  const int wr = wid >> 1, wc = wid & 1;
  const int rt = blockIdx.y, ct = blockIdx.x;

  const int srow = t >> 2, sslot = t & 3;
  const ushort* ga = A + (size_t)(rt * 128 + srow) * 1024 + sslot * 8;
  const ushort* gb = Bt + (size_t)(ct * 128 + srow) * 1024 + sslot * 8;
  ushort* lA = &As[t * 8];
  ushort* lB = &Bs[t * 8];

  f32x4 acc[4][4];
#pragma unroll
  for (int m = 0; m < 4; ++m)
#pragma unroll
    for (int n = 0; n < 4; ++n) acc[m][n] = (f32x4){0.f, 0.f, 0.f, 0.f};

  int aidx[4], bidx[4];
#pragma unroll
  for (int m = 0; m < 4; ++m) {
    int ra = wr * 64 + m * 16 + (lane & 15);
    aidx[m] = ra * 32 + ((lane >> 4) << 3);
    int rb = wc * 64 + m * 16 + (lane & 15);
    bidx[m] = rb * 32 + ((lane >> 4) << 3);
  }

  gld16(ga, lA); gld16(ga + 65536, lA + 2048);
  gld16(gb, lB); gld16(gb + 65536, lB + 2048);

  for (int kt = 0; kt < 32; ++kt) {
    __syncthreads();
    bf16x8 af[4], bfv[4];
#pragma unroll
    for (int m = 0; m < 4; ++m) af[m] = *(const bf16x8*)&As[aidx[m]];
#pragma unroll
    for (int n = 0; n < 4; ++n) bfv[n] = *(const bf16x8*)&Bs[bidx[n]];
    __syncthreads();
    if (kt < 31) {
      const ushort* ga2 = ga + (kt + 1) * 32;
      const ushort* gb2 = gb + (kt + 1) * 32;
      gld16(ga2, lA); gld16(ga2 + 65536, lA + 2048);
      gld16(gb2, lB); gld16(gb2 + 65536, lB + 2048);
    }
#pragma unroll
    for (int m = 0; m < 4; ++m)
#pragma unroll
      for (int n = 0; n < 4; ++n)
        acc[m][n] = __builtin_amdgcn_mfma_f32_16x16x32_bf16(af[m], bfv[n], acc[m][n], 0, 0, 0);
  }

  const int colb = ct * 128 + wc * 64;
  const int rowb = rt * 128 + wr * 64;
  if constexpr (MODE == 0) {
#pragma unroll
    for (int n = 0; n < 4; ++n) {
      int col = colb + n * 16 + (lane & 15);
      float bv = bias[col];
      int three = col >> 10, hx = (col >> 6) & 15, d = col & 63;
      float sc = (three == 0) ? QSCALE : 1.0f;
      ushort* dst = (three == 0) ? Q : (three == 1) ? Ko : V;
#pragma unroll
      for (int m = 0; m < 4; ++m) {
        int r0 = rowb + m * 16 + ((lane >> 4) << 2);
#pragma unroll
        for (int r = 0; r < 4; ++r) {
          int row = r0 + r;
          int b = row >> 11, s = row & 2047;
          dst[(size_t)((b * 16 + hx) * 2048 + s) * 64 + d] = f2bf((acc[m][n][r] + bv) * sc);
        }
      }
    }
  } else {
#pragma unroll
    for (int n = 0; n < 4; ++n) {
      int col = colb + n * 16 + (lane & 15);
      float bv = bias[col];
#pragma unroll
      for (int m = 0; m < 4; ++m) {
        int r0 = rowb + m * 16 + ((lane >> 4) << 2);
#pragma unroll
        for (int r = 0; r < 4; ++r)
          Out[(size_t)(r0 + r) * 1024 + col] = acc[m][n][r] + bv;
      }
    }
  }
}

// ---------------- flash attention ----------------
// grid (16 q-tiles, 32 bh) = 512 blocks. 512 threads / 8 waves, QBLK=128
// (16 q rows per wave). K [64][72] / Vt [64][72] reg-staged (+8 pad,
// conflict-free). P in XOR-swizzled [128][64] LDS, wave-private stripes.
// Softmax in log2 domain, per-lane deferred sum, defer-max rescale skip.
// __launch_bounds__ 2nd arg: EMPIRICAL on this toolchain — arg=4 caps VGPR
// at 64 (r3/r5 both spilled, WRITE_SIZE >1 GB); arg=2 allows ~96-128.
// Live set ~90 regs -> (512,2). 96-128 VGPR still reaches 4 waves/SIMD =
// 2 blocks x 8 waves per CU, exactly fed by the 512-block grid.
__global__ __launch_bounds__(512, 2) void k_attn(const ushort* __restrict__ Qb,
                                                 const ushort* __restrict__ Kb,
                                                 const ushort* __restrict__ Vtb,
                                                 ushort* __restrict__ AO) {
  __shared__ ushort Ks[64 * 72];
  __shared__ ushort Vs[64 * 72];
  __shared__ ushort Ps[128 * 64];
  const int t = threadIdx.x, lane = t & 63, wid = t >> 6;  // wid 0..7
  const int c = lane & 15, g = lane >> 4;
  const int bh = blockIdx.y, qt = blockIdx.x;
  const ushort* Qh = Qb + (size_t)bh * 131072;
  const ushort* Kh = Kb + (size_t)bh * 131072;
  const ushort* Vh = Vtb + (size_t)bh * 131072;

  bf16x8 qf[2];
#pragma unroll
  for (int kk = 0; kk < 2; ++kk) {
    int row = qt * 128 + wid * 16 + c;
    qf[kk] = *(const bf16x8*)&Qh[row * 64 + kk * 32 + g * 8];
  }

  f32x4 oacc[4];
  float mrow[4], lpart[4];
#pragma unroll
  for (int n = 0; n < 4; ++n) oacc[n] = (f32x4){0.f, 0.f, 0.f, 0.f};
#pragma unroll
  for (int r = 0; r < 4; ++r) { mrow[r] = -1e30f; lpart[r] = 0.f; }

  // staging: 512 threads x 16B = one 64x64 bf16 tile each for K and V
  const int strow = t >> 3, stcol = (t & 7) * 8;

  int kidx[4][2];
#pragma unroll
  for (int n = 0; n < 4; ++n)
#pragma unroll
    for (int kk = 0; kk < 2; ++kk)
      kidx[n][kk] = (n * 16 + c) * 72 + (kk * 4 + g) * 8;

  // P-store geometry: q = wid*16 + g*4 + r; addr = q*64 + ((n*16)^(g<<4)) + c
  const int g16 = g << 4;
  int woff[4];
#pragma unroll
  for (int n = 0; n < 4; ++n) woff[n] = ((n * 16) ^ g16) + c;
  const int qbase = (wid * 16 + g * 4) * 64;
  // P-read: row = wid*16 + c, key = (row>>2)&3 = c>>2
  int pridx[2];
#pragma unroll
  for (int kk = 0; kk < 2; ++kk)
    pridx[kk] = (wid * 16 + c) * 64 + ((kk * 32 + g * 8) ^ ((c >> 2) << 4));

  uint4 kreg, vreg;
  kreg = *(const uint4*)&Kh[(size_t)strow * 64 + stcol];
  vreg = *(const uint4*)&Vh[(size_t)strow * 2048 + stcol];

  for (int kt = 0; kt < 32; ++kt) {
    __syncthreads();  // prev tile's reads done
    *(uint4*)&Ks[strow * 72 + stcol] = kreg;
    *(uint4*)&Vs[strow * 72 + stcol] = vreg;
    __syncthreads();  // tiles ready
    if (kt < 31) {    // overlap next-tile loads with compute
      kreg = *(const uint4*)&Kh[(size_t)((kt + 1) * 64 + strow) * 64 + stcol];
      vreg = *(const uint4*)&Vh[(size_t)strow * 2048 + (kt + 1) * 64 + stcol];
    }
    // QK^T (scores already in log2 domain via Q pre-scale)
    f32x4 sacc[4];
#pragma unroll
    for (int n = 0; n < 4; ++n) sacc[n] = (f32x4){0.f, 0.f, 0.f, 0.f};
#pragma unroll
    for (int kk = 0; kk < 2; ++kk)
#pragma unroll
      for (int n = 0; n < 4; ++n) {
        bf16x8 kf = *(const bf16x8*)&Ks[kidx[n][kk]];
        sacc[n] = __builtin_amdgcn_mfma_f32_16x16x32_bf16(qf[kk], kf, sacc[n], 0, 0, 0);
      }
    // online softmax, defer-max (THR=12 in log2), per-lane deferred sum
#pragma unroll
    for (int r = 0; r < 4; ++r) {
      float s0 = sacc[0][r], s1 = sacc[1][r], s2 = sacc[2][r], s3 = sacc[3][r];
      float mx = fmaxf(fmaxf(s0, s1), fmaxf(s2, s3));
#pragma unroll
      for (int off = 1; off < 16; off <<= 1) mx = fmaxf(mx, __shfl_xor(mx, off));
      float mo = mrow[r];
      float p0, p1, p2, p3;
      if (__all(mx <= mo + 12.0f)) {
        p0 = EXP2F(s0 - mo); p1 = EXP2F(s1 - mo);
        p2 = EXP2F(s2 - mo); p3 = EXP2F(s3 - mo);
        lpart[r] += (p0 + p1) + (p2 + p3);
      } else {
        float mn = fmaxf(mo, mx);
        float corr = EXP2F(mo - mn);
        mrow[r] = mn;
        p0 = EXP2F(s0 - mn); p1 = EXP2F(s1 - mn);
        p2 = EXP2F(s2 - mn); p3 = EXP2F(s3 - mn);
        lpart[r] = lpart[r] * corr + ((p0 + p1) + (p2 + p3));
        oacc[0][r] *= corr; oacc[1][r] *= corr;
        oacc[2][r] *= corr; oacc[3][r] *= corr;
      }
      int pb = qbase + r * 64;
      Ps[pb + woff[0]] = f2bf(p0); Ps[pb + woff[1]] = f2bf(p1);
      Ps[pb + woff[2]] = f2bf(p2); Ps[pb + woff[3]] = f2bf(p3);
    }
    // PV (P stripe is wave-private; same-wave ds ordering -> no barrier)
#pragma unroll
    for (int kk = 0; kk < 2; ++kk) {
      bf16x8 pa = *(const bf16x8*)&Ps[pridx[kk]];
#pragma unroll
      for (int nd = 0; nd < 4; ++nd) {
        bf16x8 vf = *(const bf16x8*)&Vs[kidx[nd][kk]];
        oacc[nd] = __builtin_amdgcn_mfma_f32_16x16x32_bf16(pa, vf, oacc[nd], 0, 0, 0);
      }
    }
  }

  const int b = bh >> 4, h = bh & 15;
  float inv[4];
#pragma unroll
  for (int r = 0; r < 4; ++r) {
#pragma unroll
    for (int off = 1; off < 16; off <<= 1) lpart[r] += __shfl_xor(lpart[r], off);
    inv[r] = 1.0f / lpart[r];
  }
#pragma unroll
  for (int nd = 0; nd < 4; ++nd) {
    int d = nd * 16 + c;
#pragma unroll
    for (int r = 0; r < 4; ++r) {
      int s = qt * 128 + wid * 16 + g * 4 + r;
      AO[(size_t)((b * 2048 + s) * 16 + h) * 64 + d] = f2bf(oacc[nd][r] * inv[r]);
    }
  }
}

extern "C" void kernel_launch(void* const* d_in, const int* in_sizes, int n_in,
                              void* d_out, int out_size, void* d_ws, size_t ws_size,
                              hipStream_t stream) {
  const float* x = (const float*)d_in[0];
  const float* w_qkv = (const float*)d_in[1];
  const float* b_qkv = (const float*)d_in[2];
  const float* w_out = (const float*)d_in[3];
  const float* b_out = (const float*)d_in[4];
  float* out = (float*)d_out;

  char* p = (char*)d_ws;
  ushort* xb = (ushort*)p;    p += (size_t)4096 * 1024 * 2;   // reused as AO later
  ushort* wqkvT = (ushort*)p; p += (size_t)3072 * 1024 * 2;
  ushort* woutT = (ushort*)p; p += (size_t)1024 * 1024 * 2;
  ushort* Qb = (ushort*)p;    p += (size_t)32 * 2048 * 64 * 2;
  ushort* Kb = (ushort*)p;    p += (size_t)32 * 2048 * 64 * 2;
  ushort* Vb = (ushort*)p;    p += (size_t)32 * 2048 * 64 * 2;
  ushort* Vtb = (ushort*)p;   p += (size_t)32 * 2048 * 64 * 2;
  ushort* AO = xb;  // xb dead after QKV GEMM; reuse (stream-ordered, safe)

  k_cast_bf16<<<2048, 256, 0, stream>>>(x, xb);
  k_transpose_cast<<<dim3(96, 32), 256, 0, stream>>>(w_qkv, wqkvT, 1024, 3072);
  k_transpose_cast<<<dim3(32, 32), 256, 0, stream>>>(w_out, woutT, 1024, 1024);
  k_gemm<0><<<dim3(24, 32), 256, 0, stream>>>(xb, wqkvT, b_qkv, Qb, Kb, Vb, nullptr);
  k_vtrans<<<dim3(32, 32), 256, 0, stream>>>(Vb, Vtb);
  k_attn<<<dim3(16, 32), 512, 0, stream>>>(Qb, Kb, Vtb, AO);
  k_gemm<1><<<dim3(8, 32), 256, 0, stream>>>(AO, woutT, b_out, nullptr, nullptr, nullptr, out);
}

// Round 7
// 136.464 us; speedup vs baseline: 3.8871x; 1.5068x over previous
//
#include <hip/hip_runtime.h>
#include <stdint.h>

typedef short bf16x8 __attribute__((ext_vector_type(8)));
typedef float f32x4 __attribute__((ext_vector_type(4)));

#if __has_builtin(__builtin_amdgcn_exp2f)
#define EXP2F(x) __builtin_amdgcn_exp2f(x)
#else
#define EXP2F(x) exp2f(x)
#endif

// 0.125 (1/sqrt(64)) * log2(e): folded into Q so QK^T scores come out in
// log2 domain directly (softmax uses native v_exp_f32 = exp2).
#define QSCALE 0.18033688011112042f

__device__ __forceinline__ unsigned short f2bf(float f) {
  unsigned u = __float_as_uint(f);
  u += 0x7fffu + ((u >> 16) & 1u);
  return (unsigned short)(u >> 16);
}

// pack 2 fp32 -> 2 bf16 in one dword (RNE), single VALU op
__device__ __forceinline__ unsigned cvtpk(float lo, float hi) {
  unsigned r;
  asm("v_cvt_pk_bf16_f32 %0, %1, %2" : "=v"(r) : "v"(lo), "v"(hi));
  return r;
}

// async global->LDS, 16B per lane; LDS dest = waveBase + lane*16 (call sites
// pass &buf[t*8], t = wid*64+lane -> consistent).
__device__ __forceinline__ void gld16(const ushort* g, ushort* l) {
  __builtin_amdgcn_global_load_lds(
      (__attribute__((address_space(1))) void*)g,
      (__attribute__((address_space(3))) void*)l, 16, 0, 0);
}

// ---------------- prep kernels ----------------
__global__ __launch_bounds__(256) void k_cast_bf16(const float* __restrict__ in,
                                                   ushort* __restrict__ out) {
  int i = (blockIdx.x * 256 + threadIdx.x) * 8;
  float4 a = *(const float4*)(in + i);
  float4 b = *(const float4*)(in + i + 4);
  union { ushort u[8]; uint4 q; } r;
  r.u[0] = f2bf(a.x); r.u[1] = f2bf(a.y); r.u[2] = f2bf(a.z); r.u[3] = f2bf(a.w);
  r.u[4] = f2bf(b.x); r.u[5] = f2bf(b.y); r.u[6] = f2bf(b.z); r.u[7] = f2bf(b.w);
  *(uint4*)(out + i) = r.q;
}

// fp32 [R][C] -> bf16 [C][R]
__global__ __launch_bounds__(256) void k_transpose_cast(const float* __restrict__ in,
                                                        ushort* __restrict__ out,
                                                        int R, int C) {
  __shared__ float tl[32][33];
  int t = threadIdx.x;
  {
    int r = t >> 3, c4 = (t & 7) * 4;
    float4 v = *(const float4*)(in + (size_t)(blockIdx.y * 32 + r) * C + blockIdx.x * 32 + c4);
    tl[r][c4] = v.x; tl[r][c4 + 1] = v.y; tl[r][c4 + 2] = v.z; tl[r][c4 + 3] = v.w;
  }
  __syncthreads();
  {
    int c = t >> 3, r4 = (t & 7) * 4;
    union { ushort u[4]; uint2 q; } o;
    o.u[0] = f2bf(tl[r4][c]);     o.u[1] = f2bf(tl[r4 + 1][c]);
    o.u[2] = f2bf(tl[r4 + 2][c]); o.u[3] = f2bf(tl[r4 + 3][c]);
    *(uint2*)(out + (size_t)(blockIdx.x * 32 + c) * R + blockIdx.y * 32 + r4) = o.q;
  }
}

// V [bh][2048][64] -> Vt [bh][64][2048]
__global__ __launch_bounds__(256) void k_vtrans(const ushort* __restrict__ V,
                                                ushort* __restrict__ Vt) {
  __shared__ ushort tl[64 * 72];
  int t = threadIdx.x;
  const ushort* inp = V + (size_t)blockIdx.y * 131072 + blockIdx.x * 4096;
#pragma unroll
  for (int p = 0; p < 2; ++p) {
    int r = (t >> 3) + p * 32, c8 = (t & 7) * 8;
    *(uint4*)&tl[r * 72 + c8] = *(const uint4*)&inp[r * 64 + c8];
  }
  __syncthreads();
  ushort* outp = Vt + (size_t)blockIdx.y * 131072 + blockIdx.x * 64;
#pragma unroll
  for (int p = 0; p < 2; ++p) {
    int d = (t >> 3) + p * 32, s8 = (t & 7) * 8;
    union { ushort u[8]; uint4 q; } o;
#pragma unroll
    for (int j = 0; j < 8; ++j) o.u[j] = tl[(s8 + j) * 72 + d];
    *(uint4*)&outp[d * 2048 + s8] = o.q;
  }
}

// ---------------- GEMM: A[M][1024] bf16 x Bt[N][1024] bf16 ----------------
// m97-verified pattern: LINEAR LDS (no swizzle) + global_load_lds width 16.
// 128x128 tile, BK=32, 4 waves (2x2), each wave 64x64 (4x4 of 16x16 frags).
// MODE 0 epilogue scales the Q third by QSCALE (log2-domain softmax).
template <int MODE>
__global__ __launch_bounds__(256, 2) void k_gemm(
    const ushort* __restrict__ A, const ushort* __restrict__ Bt,
    const float* __restrict__ bias, ushort* __restrict__ Q,
    ushort* __restrict__ Ko, ushort* __restrict__ V, float* __restrict__ Out) {
  __shared__ ushort As[128 * 32];
  __shared__ ushort Bs[128 * 32];
  const int t = threadIdx.x;
  const int lane = t & 63, wid = t >> 6;
  const int wr = wid >> 1, wc = wid & 1;
  const int rt = blockIdx.y, ct = blockIdx.x;

  const int srow = t >> 2, sslot = t & 3;
  const ushort* ga = A + (size_t)(rt * 128 + srow) * 1024 + sslot * 8;
  const ushort* gb = Bt + (size_t)(ct * 128 + srow) * 1024 + sslot * 8;
  ushort* lA = &As[t * 8];
  ushort* lB = &Bs[t * 8];

  f32x4 acc[4][4];
#pragma unroll
  for (int m = 0; m < 4; ++m)
#pragma unroll
    for (int n = 0; n < 4; ++n) acc[m][n] = (f32x4){0.f, 0.f, 0.f, 0.f};

  int aidx[4], bidx[4];
#pragma unroll
  for (int m = 0; m < 4; ++m) {
    int ra = wr * 64 + m * 16 + (lane & 15);
    aidx[m] = ra * 32 + ((lane >> 4) << 3);
    int rb = wc * 64 + m * 16 + (lane & 15);
    bidx[m] = rb * 32 + ((lane >> 4) << 3);
  }

  gld16(ga, lA); gld16(ga + 65536, lA + 2048);
  gld16(gb, lB); gld16(gb + 65536, lB + 2048);

  for (int kt = 0; kt < 32; ++kt) {
    __syncthreads();
    bf16x8 af[4], bfv[4];
#pragma unroll
    for (int m = 0; m < 4; ++m) af[m] = *(const bf16x8*)&As[aidx[m]];
#pragma unroll
    for (int n = 0; n < 4; ++n) bfv[n] = *(const bf16x8*)&Bs[bidx[n]];
    __syncthreads();
    if (kt < 31) {
      const ushort* ga2 = ga + (kt + 1) * 32;
      const ushort* gb2 = gb + (kt + 1) * 32;
      gld16(ga2, lA); gld16(ga2 + 65536, lA + 2048);
      gld16(gb2, lB); gld16(gb2 + 65536, lB + 2048);
    }
#pragma unroll
    for (int m = 0; m < 4; ++m)
#pragma unroll
      for (int n = 0; n < 4; ++n)
        acc[m][n] = __builtin_amdgcn_mfma_f32_16x16x32_bf16(af[m], bfv[n], acc[m][n], 0, 0, 0);
  }

  const int colb = ct * 128 + wc * 64;
  const int rowb = rt * 128 + wr * 64;
  if constexpr (MODE == 0) {
#pragma unroll
    for (int n = 0; n < 4; ++n) {
      int col = colb + n * 16 + (lane & 15);
      float bv = bias[col];
      int three = col >> 10, hx = (col >> 6) & 15, d = col & 63;
      float sc = (three == 0) ? QSCALE : 1.0f;
      ushort* dst = (three == 0) ? Q : (three == 1) ? Ko : V;
#pragma unroll
      for (int m = 0; m < 4; ++m) {
        int r0 = rowb + m * 16 + ((lane >> 4) << 2);
#pragma unroll
        for (int r = 0; r < 4; ++r) {
          int row = r0 + r;
          int b = row >> 11, s = row & 2047;
          dst[(size_t)((b * 16 + hx) * 2048 + s) * 64 + d] = f2bf((acc[m][n][r] + bv) * sc);
        }
      }
    }
  } else {
#pragma unroll
    for (int n = 0; n < 4; ++n) {
      int col = colb + n * 16 + (lane & 15);
      float bv = bias[col];
#pragma unroll
      for (int m = 0; m < 4; ++m) {
        int r0 = rowb + m * 16 + ((lane >> 4) << 2);
#pragma unroll
        for (int r = 0; r < 4; ++r)
          Out[(size_t)(r0 + r) * 1024 + col] = acc[m][n][r] + bv;
      }
    }
  }
}

// ---------------- flash attention (swapped-QK^T in-register softmax) -------
// grid (16 q-tiles, 32 bh) = 512 blocks, 512 thr / 8 waves, QBLK=128.
// SWAPPED QK^T: sacc[n] = mfma(K_frag, Q_frag) -> lane (c,g) holds 16 scores
// of ONE q-row (q = wid*16+c), k = n*16+g*4+r. Row max = in-lane tree + 2
// shfl_xor; sum = per-lane deferred (0 shuffles in loop). P packed via
// v_cvt_pk_bf16_f32 (8 ops vs 16 f2bf) into XOR-swizzled Ps[128][64]
// (byte key (c&14)<<3: write=4x ds_write_b64 2-way banks, read=2x
// ds_read_b128 16B-aligned, same key+row both sides -> bijective).
// K [64][72] / Vt [64][72] reg-staged (+8 pad). Defer-max THR=12 (log2).
// T5 setprio around MFMA clusters. All P traffic is wave-private rows;
// same-wave in-order DS pipe -> no extra barrier (r2-r6-verified property).
__global__ __launch_bounds__(512, 2) void k_attn(const ushort* __restrict__ Qb,
                                                 const ushort* __restrict__ Kb,
                                                 const ushort* __restrict__ Vtb,
                                                 ushort* __restrict__ AO) {
  __shared__ ushort Ks[64 * 72];
  __shared__ ushort Vs[64 * 72];
  __shared__ ushort Ps[128 * 64];
  const int t = threadIdx.x, lane = t & 63, wid = t >> 6;  // wid 0..7
  const int c = lane & 15, g = lane >> 4;
  const int bh = blockIdx.y, qt = blockIdx.x;
  const ushort* Qh = Qb + (size_t)bh * 131072;
  const ushort* Kh = Kb + (size_t)bh * 131072;
  const ushort* Vh = Vtb + (size_t)bh * 131072;

  bf16x8 qf[2];
#pragma unroll
  for (int kk = 0; kk < 2; ++kk) {
    int row = qt * 128 + wid * 16 + c;
    qf[kk] = *(const bf16x8*)&Qh[row * 64 + kk * 32 + g * 8];
  }

  f32x4 oacc[4];
#pragma unroll
  for (int n = 0; n < 4; ++n) oacc[n] = (f32x4){0.f, 0.f, 0.f, 0.f};
  float mrow = -1e30f, lpart = 0.f;  // state for q = wid*16+c (per lane)

  // staging: 512 threads x 16B = one 64x64 bf16 tile each for K and V
  const int strow = t >> 3, stcol = (t & 7) * 8;

  // K (QK^T A-frag) and Vt (PV B-frag) read offsets — same pattern
  int kidx[4][2];
#pragma unroll
  for (int n = 0; n < 4; ++n)
#pragma unroll
    for (int kk = 0; kk < 2; ++kk)
      kidx[n][kk] = (n * 16 + c) * 72 + (kk * 4 + g) * 8;

  // P LDS offsets (ushort units), row = own q, XOR key on 4-ushort groups
  const int prow = wid * 16 + c;
  const int keyu = (c & 14) << 2;  // byte key (c&14)<<3
  int psw[4], prd[2];
#pragma unroll
  for (int n = 0; n < 4; ++n) psw[n] = prow * 64 + ((n * 16 + g * 4) ^ keyu);
#pragma unroll
  for (int kk = 0; kk < 2; ++kk) prd[kk] = prow * 64 + ((kk * 32 + g * 8) ^ keyu);

  uint4 kreg, vreg;
  kreg = *(const uint4*)&Kh[(size_t)strow * 64 + stcol];
  vreg = *(const uint4*)&Vh[(size_t)strow * 2048 + stcol];

  for (int kt = 0; kt < 32; ++kt) {
    __syncthreads();  // prev tile's reads done
    *(uint4*)&Ks[strow * 72 + stcol] = kreg;
    *(uint4*)&Vs[strow * 72 + stcol] = vreg;
    __syncthreads();  // tiles ready
    if (kt < 31) {    // overlap next-tile loads with compute
      kreg = *(const uint4*)&Kh[(size_t)((kt + 1) * 64 + strow) * 64 + stcol];
      vreg = *(const uint4*)&Vh[(size_t)strow * 2048 + (kt + 1) * 64 + stcol];
    }
    // QK^T swapped: sacc[n] lane(c,g) reg r = S[q=wid*16+c][k=n*16+g*4+r]
    f32x4 sacc[4];
#pragma unroll
    for (int n = 0; n < 4; ++n) sacc[n] = (f32x4){0.f, 0.f, 0.f, 0.f};
    __builtin_amdgcn_s_setprio(1);
#pragma unroll
    for (int kk = 0; kk < 2; ++kk)
#pragma unroll
      for (int n = 0; n < 4; ++n) {
        bf16x8 kf = *(const bf16x8*)&Ks[kidx[n][kk]];
        sacc[n] = __builtin_amdgcn_mfma_f32_16x16x32_bf16(kf, qf[kk], sacc[n], 0, 0, 0);
      }
    __builtin_amdgcn_s_setprio(0);
    // in-lane row max (16 values, one q-row) + 2 cross-g shuffles
    float mx0 = fmaxf(fmaxf(sacc[0][0], sacc[0][1]), fmaxf(sacc[0][2], sacc[0][3]));
    float mx1 = fmaxf(fmaxf(sacc[1][0], sacc[1][1]), fmaxf(sacc[1][2], sacc[1][3]));
    float mx2 = fmaxf(fmaxf(sacc[2][0], sacc[2][1]), fmaxf(sacc[2][2], sacc[2][3]));
    float mx3 = fmaxf(fmaxf(sacc[3][0], sacc[3][1]), fmaxf(sacc[3][2], sacc[3][3]));
    float mx = fmaxf(fmaxf(mx0, mx1), fmaxf(mx2, mx3));
    mx = fmaxf(mx, __shfl_xor(mx, 16));
    mx = fmaxf(mx, __shfl_xor(mx, 32));
    // defer-max: rescale only when the running max grew past THR=12 (log2)
    if (!__all(mx <= mrow + 12.0f)) {
      float mo = mrow;
      float mn = fmaxf(mo, mx);
      float corr = EXP2F(mo - mn);  // corr for q = c
      mrow = mn;
      lpart *= corr;
#pragma unroll
      for (int r = 0; r < 4; ++r) {  // oacc rows are q = g*4+r -> redistribute
        float cr = __shfl(corr, (g << 2) + r);
        oacc[0][r] *= cr; oacc[1][r] *= cr; oacc[2][r] *= cr; oacc[3][r] *= cr;
      }
    }
    const float mu = mrow;
    float p[4][4];
#pragma unroll
    for (int n = 0; n < 4; ++n)
#pragma unroll
      for (int r = 0; r < 4; ++r) p[n][r] = EXP2F(sacc[n][r] - mu);
    lpart += ((p[0][0] + p[0][1]) + (p[0][2] + p[0][3])) +
             ((p[1][0] + p[1][1]) + (p[1][2] + p[1][3])) +
             ((p[2][0] + p[2][1]) + (p[2][2] + p[2][3])) +
             ((p[3][0] + p[3][1]) + (p[3][2] + p[3][3]));
    // pack to bf16 pairs and store own-row P (4x ds_write_b64, 2-way banks)
#pragma unroll
    for (int n = 0; n < 4; ++n) {
      uint2 w;
      w.x = cvtpk(p[n][0], p[n][1]);
      w.y = cvtpk(p[n][2], p[n][3]);
      *(uint2*)&Ps[psw[n]] = w;
    }
    // PV: A-frag = own-row P (2x ds_read_b128), B-frag = Vt rows
    __builtin_amdgcn_s_setprio(1);
#pragma unroll
    for (int kk = 0; kk < 2; ++kk) {
      bf16x8 pa = *(const bf16x8*)&Ps[prd[kk]];
#pragma unroll
      for (int nd = 0; nd < 4; ++nd) {
        bf16x8 vf = *(const bf16x8*)&Vs[kidx[nd][kk]];
        oacc[nd] = __builtin_amdgcn_mfma_f32_16x16x32_bf16(pa, vf, oacc[nd], 0, 0, 0);
      }
    }
    __builtin_amdgcn_s_setprio(0);
  }

  const int b = bh >> 4, h = bh & 15;
  lpart += __shfl_xor(lpart, 16);
  lpart += __shfl_xor(lpart, 32);
  float inv = 1.0f / lpart;  // for q = c
  float invr[4];
#pragma unroll
  for (int r = 0; r < 4; ++r) invr[r] = __shfl(inv, (g << 2) + r);
#pragma unroll
  for (int nd = 0; nd < 4; ++nd) {
    int d = nd * 16 + c;
#pragma unroll
    for (int r = 0; r < 4; ++r) {
      int s = qt * 128 + wid * 16 + (g << 2) + r;
      AO[(size_t)((b * 2048 + s) * 16 + h) * 64 + d] = f2bf(oacc[nd][r] * invr[r]);
    }
  }
}

extern "C" void kernel_launch(void* const* d_in, const int* in_sizes, int n_in,
                              void* d_out, int out_size, void* d_ws, size_t ws_size,
                              hipStream_t stream) {
  const float* x = (const float*)d_in[0];
  const float* w_qkv = (const float*)d_in[1];
  const float* b_qkv = (const float*)d_in[2];
  const float* w_out = (const float*)d_in[3];
  const float* b_out = (const float*)d_in[4];
  float* out = (float*)d_out;

  char* p = (char*)d_ws;
  ushort* xb = (ushort*)p;    p += (size_t)4096 * 1024 * 2;   // reused as AO later
  ushort* wqkvT = (ushort*)p; p += (size_t)3072 * 1024 * 2;
  ushort* woutT = (ushort*)p; p += (size_t)1024 * 1024 * 2;
  ushort* Qb = (ushort*)p;    p += (size_t)32 * 2048 * 64 * 2;
  ushort* Kb = (ushort*)p;    p += (size_t)32 * 2048 * 64 * 2;
  ushort* Vb = (ushort*)p;    p += (size_t)32 * 2048 * 64 * 2;
  ushort* Vtb = (ushort*)p;   p += (size_t)32 * 2048 * 64 * 2;
  ushort* AO = xb;  // xb dead after QKV GEMM; reuse (stream-ordered, safe)

  k_cast_bf16<<<2048, 256, 0, stream>>>(x, xb);
  k_transpose_cast<<<dim3(96, 32), 256, 0, stream>>>(w_qkv, wqkvT, 1024, 3072);
  k_transpose_cast<<<dim3(32, 32), 256, 0, stream>>>(w_out, woutT, 1024, 1024);
  k_gemm<0><<<dim3(24, 32), 256, 0, stream>>>(xb, wqkvT, b_qkv, Qb, Kb, Vb, nullptr);
  k_vtrans<<<dim3(32, 32), 256, 0, stream>>>(Vb, Vtb);
  k_attn<<<dim3(16, 32), 512, 0, stream>>>(Qb, Kb, Vtb, AO);
  k_gemm<1><<<dim3(8, 32), 256, 0, stream>>>(AO, woutT, b_out, nullptr, nullptr, nullptr, out);
}

// Round 8
// 134.559 us; speedup vs baseline: 3.9422x; 1.0142x over previous
//
#include <hip/hip_runtime.h>
#include <stdint.h>

typedef short bf16x8 __attribute__((ext_vector_type(8)));
typedef float f32x4 __attribute__((ext_vector_type(4)));

#if __has_builtin(__builtin_amdgcn_exp2f)
#define EXP2F(x) __builtin_amdgcn_exp2f(x)
#else
#define EXP2F(x) exp2f(x)
#endif

// 0.125 (1/sqrt(64)) * log2(e): folded into Q so QK^T scores come out in
// log2 domain directly (softmax uses native v_exp_f32 = exp2).
#define QSCALE 0.18033688011112042f

__device__ __forceinline__ unsigned short f2bf(float f) {
  unsigned u = __float_as_uint(f);
  u += 0x7fffu + ((u >> 16) & 1u);
  return (unsigned short)(u >> 16);
}

// pack 2 fp32 -> 2 bf16 in one dword (RNE), single VALU op
__device__ __forceinline__ unsigned cvtpk(float lo, float hi) {
  unsigned r;
  asm("v_cvt_pk_bf16_f32 %0, %1, %2" : "=v"(r) : "v"(lo), "v"(hi));
  return r;
}

// async global->LDS, 16B per lane; LDS dest = waveBase + lane*16 (call sites
// pass &buf[t*8], t = wid*64+lane -> consistent).
__device__ __forceinline__ void gld16(const ushort* g, ushort* l) {
  __builtin_amdgcn_global_load_lds(
      (__attribute__((address_space(1))) void*)g,
      (__attribute__((address_space(3))) void*)l, 16, 0, 0);
}

// ---------------- prep kernels ----------------
__global__ __launch_bounds__(256) void k_cast_bf16(const float* __restrict__ in,
                                                   ushort* __restrict__ out) {
  int i = (blockIdx.x * 256 + threadIdx.x) * 8;
  float4 a = *(const float4*)(in + i);
  float4 b = *(const float4*)(in + i + 4);
  union { ushort u[8]; uint4 q; } r;
  r.u[0] = f2bf(a.x); r.u[1] = f2bf(a.y); r.u[2] = f2bf(a.z); r.u[3] = f2bf(a.w);
  r.u[4] = f2bf(b.x); r.u[5] = f2bf(b.y); r.u[6] = f2bf(b.z); r.u[7] = f2bf(b.w);
  *(uint4*)(out + i) = r.q;
}

// fp32 [R][C] -> bf16 [C][R]
__global__ __launch_bounds__(256) void k_transpose_cast(const float* __restrict__ in,
                                                        ushort* __restrict__ out,
                                                        int R, int C) {
  __shared__ float tl[32][33];
  int t = threadIdx.x;
  {
    int r = t >> 3, c4 = (t & 7) * 4;
    float4 v = *(const float4*)(in + (size_t)(blockIdx.y * 32 + r) * C + blockIdx.x * 32 + c4);
    tl[r][c4] = v.x; tl[r][c4 + 1] = v.y; tl[r][c4 + 2] = v.z; tl[r][c4 + 3] = v.w;
  }
  __syncthreads();
  {
    int c = t >> 3, r4 = (t & 7) * 4;
    union { ushort u[4]; uint2 q; } o;
    o.u[0] = f2bf(tl[r4][c]);     o.u[1] = f2bf(tl[r4 + 1][c]);
    o.u[2] = f2bf(tl[r4 + 2][c]); o.u[3] = f2bf(tl[r4 + 3][c]);
    *(uint2*)(out + (size_t)(blockIdx.x * 32 + c) * R + blockIdx.y * 32 + r4) = o.q;
  }
}

// V [bh][2048][64] -> Vt [bh][64][2048]
__global__ __launch_bounds__(256) void k_vtrans(const ushort* __restrict__ V,
                                                ushort* __restrict__ Vt) {
  __shared__ ushort tl[64 * 72];
  int t = threadIdx.x;
  const ushort* inp = V + (size_t)blockIdx.y * 131072 + blockIdx.x * 4096;
#pragma unroll
  for (int p = 0; p < 2; ++p) {
    int r = (t >> 3) + p * 32, c8 = (t & 7) * 8;
    *(uint4*)&tl[r * 72 + c8] = *(const uint4*)&inp[r * 64 + c8];
  }
  __syncthreads();
  ushort* outp = Vt + (size_t)blockIdx.y * 131072 + blockIdx.x * 64;
#pragma unroll
  for (int p = 0; p < 2; ++p) {
    int d = (t >> 3) + p * 32, s8 = (t & 7) * 8;
    union { ushort u[8]; uint4 q; } o;
#pragma unroll
    for (int j = 0; j < 8; ++j) o.u[j] = tl[(s8 + j) * 72 + d];
    *(uint4*)&outp[d * 2048 + s8] = o.q;
  }
}

// ---------------- GEMM: A[M][1024] bf16 x Bt[N][1024] bf16 ----------------
// m97-verified pattern: LINEAR LDS (no swizzle) + global_load_lds width 16.
// 128x128 tile, BK=32, 4 waves (2x2), each wave 64x64 (4x4 of 16x16 frags).
// MODE 0 epilogue scales the Q third by QSCALE (log2-domain softmax).
template <int MODE>
__global__ __launch_bounds__(256, 2) void k_gemm(
    const ushort* __restrict__ A, const ushort* __restrict__ Bt,
    const float* __restrict__ bias, ushort* __restrict__ Q,
    ushort* __restrict__ Ko, ushort* __restrict__ V, float* __restrict__ Out) {
  __shared__ ushort As[128 * 32];
  __shared__ ushort Bs[128 * 32];
  const int t = threadIdx.x;
  const int lane = t & 63, wid = t >> 6;
  const int wr = wid >> 1, wc = wid & 1;
  const int rt = blockIdx.y, ct = blockIdx.x;

  const int srow = t >> 2, sslot = t & 3;
  const ushort* ga = A + (size_t)(rt * 128 + srow) * 1024 + sslot * 8;
  const ushort* gb = Bt + (size_t)(ct * 128 + srow) * 1024 + sslot * 8;
  ushort* lA = &As[t * 8];
  ushort* lB = &Bs[t * 8];

  f32x4 acc[4][4];
#pragma unroll
  for (int m = 0; m < 4; ++m)
#pragma unroll
    for (int n = 0; n < 4; ++n) acc[m][n] = (f32x4){0.f, 0.f, 0.f, 0.f};

  int aidx[4], bidx[4];
#pragma unroll
  for (int m = 0; m < 4; ++m) {
    int ra = wr * 64 + m * 16 + (lane & 15);
    aidx[m] = ra * 32 + ((lane >> 4) << 3);
    int rb = wc * 64 + m * 16 + (lane & 15);
    bidx[m] = rb * 32 + ((lane >> 4) << 3);
  }

  gld16(ga, lA); gld16(ga + 65536, lA + 2048);
  gld16(gb, lB); gld16(gb + 65536, lB + 2048);

  for (int kt = 0; kt < 32; ++kt) {
    __syncthreads();
    bf16x8 af[4], bfv[4];
#pragma unroll
    for (int m = 0; m < 4; ++m) af[m] = *(const bf16x8*)&As[aidx[m]];
#pragma unroll
    for (int n = 0; n < 4; ++n) bfv[n] = *(const bf16x8*)&Bs[bidx[n]];
    __syncthreads();
    if (kt < 31) {
      const ushort* ga2 = ga + (kt + 1) * 32;
      const ushort* gb2 = gb + (kt + 1) * 32;
      gld16(ga2, lA); gld16(ga2 + 65536, lA + 2048);
      gld16(gb2, lB); gld16(gb2 + 65536, lB + 2048);
    }
#pragma unroll
    for (int m = 0; m < 4; ++m)
#pragma unroll
      for (int n = 0; n < 4; ++n)
        acc[m][n] = __builtin_amdgcn_mfma_f32_16x16x32_bf16(af[m], bfv[n], acc[m][n], 0, 0, 0);
  }

  const int colb = ct * 128 + wc * 64;
  const int rowb = rt * 128 + wr * 64;
  if constexpr (MODE == 0) {
#pragma unroll
    for (int n = 0; n < 4; ++n) {
      int col = colb + n * 16 + (lane & 15);
      float bv = bias[col];
      int three = col >> 10, hx = (col >> 6) & 15, d = col & 63;
      float sc = (three == 0) ? QSCALE : 1.0f;
      ushort* dst = (three == 0) ? Q : (three == 1) ? Ko : V;
#pragma unroll
      for (int m = 0; m < 4; ++m) {
        int r0 = rowb + m * 16 + ((lane >> 4) << 2);
#pragma unroll
        for (int r = 0; r < 4; ++r) {
          int row = r0 + r;
          int b = row >> 11, s = row & 2047;
          dst[(size_t)((b * 16 + hx) * 2048 + s) * 64 + d] = f2bf((acc[m][n][r] + bv) * sc);
        }
      }
    }
  } else {
#pragma unroll
    for (int n = 0; n < 4; ++n) {
      int col = colb + n * 16 + (lane & 15);
      float bv = bias[col];
#pragma unroll
      for (int m = 0; m < 4; ++m) {
        int r0 = rowb + m * 16 + ((lane >> 4) << 2);
#pragma unroll
        for (int r = 0; r < 4; ++r)
          Out[(size_t)(r0 + r) * 1024 + col] = acc[m][n][r] + bv;
      }
    }
  }
}

// ---------------- flash attention (swapped-QK^T, K/V double-buffered) ------
// grid (16 q-tiles, 32 bh) = 512 blocks, 512 thr / 8 waves, QBLK=128.
// SWAPPED QK^T: sacc[n] = mfma(K_frag, Q_frag) -> lane (c,g) holds 16 scores
// of ONE q-row (q = wid*16+c). Row max = in-lane tree + 2 shfl_xor; sum =
// per-lane deferred. P packed via v_cvt_pk_bf16_f32 into XOR-swizzled
// Ps[128][64] (wave-private rows; same-wave DS in-order -> no barrier).
// K/V DOUBLE-BUFFERED (r8): one barrier per tile; schedule per tile =
// { compute(buf[cur]) ; ds_write prefetched tile -> buf[cur^1] ; issue
// global loads tile+2 ; barrier ; flip }. Staging write overlaps other
// waves' compute (different buffer -> race-free); load latency hides under
// a full compute phase. LDS 52 KB (<64), 2 blocks/CU (grid-fed).
// __launch_bounds__ 2nd arg: EMPIRICAL — arg=4 caps VGPR at 64 (spills);
// arg=2 allows ~96-128. r7 live set: VGPR_Count=44.
__global__ __launch_bounds__(512, 2) void k_attn(const ushort* __restrict__ Qb,
                                                 const ushort* __restrict__ Kb,
                                                 const ushort* __restrict__ Vtb,
                                                 ushort* __restrict__ AO) {
  __shared__ ushort Ks[2][64 * 72];
  __shared__ ushort Vs[2][64 * 72];
  __shared__ ushort Ps[128 * 64];
  const int t = threadIdx.x, lane = t & 63, wid = t >> 6;  // wid 0..7
  const int c = lane & 15, g = lane >> 4;
  const int bh = blockIdx.y, qt = blockIdx.x;
  const ushort* Qh = Qb + (size_t)bh * 131072;
  const ushort* Kh = Kb + (size_t)bh * 131072;
  const ushort* Vh = Vtb + (size_t)bh * 131072;

  bf16x8 qf[2];
#pragma unroll
  for (int kk = 0; kk < 2; ++kk) {
    int row = qt * 128 + wid * 16 + c;
    qf[kk] = *(const bf16x8*)&Qh[row * 64 + kk * 32 + g * 8];
  }

  f32x4 oacc[4];
#pragma unroll
  for (int n = 0; n < 4; ++n) oacc[n] = (f32x4){0.f, 0.f, 0.f, 0.f};
  float mrow = -1e30f, lpart = 0.f;  // state for q = wid*16+c (per lane)

  // staging: 512 threads x 16B = one 64x64 bf16 tile each for K and V
  const int strow = t >> 3, stcol = (t & 7) * 8;
  const int stoff = strow * 72 + stcol;

  // K (QK^T A-frag) and Vt (PV B-frag) read offsets — same pattern
  int kidx[4][2];
#pragma unroll
  for (int n = 0; n < 4; ++n)
#pragma unroll
    for (int kk = 0; kk < 2; ++kk)
      kidx[n][kk] = (n * 16 + c) * 72 + (kk * 4 + g) * 8;

  // P LDS offsets (ushort units), row = own q, XOR key on 4-ushort groups
  const int prow = wid * 16 + c;
  const int keyu = (c & 14) << 2;  // byte key (c&14)<<3
  int psw[4], prd[2];
#pragma unroll
  for (int n = 0; n < 4; ++n) psw[n] = prow * 64 + ((n * 16 + g * 4) ^ keyu);
#pragma unroll
  for (int kk = 0; kk < 2; ++kk) prd[kk] = prow * 64 + ((kk * 32 + g * 8) ^ keyu);

  // prologue: tile 0 -> LDS buf0; tile 1 -> regs
  uint4 kreg = *(const uint4*)&Kh[(size_t)strow * 64 + stcol];
  uint4 vreg = *(const uint4*)&Vh[(size_t)strow * 2048 + stcol];
  *(uint4*)&Ks[0][stoff] = kreg;
  *(uint4*)&Vs[0][stoff] = vreg;
  kreg = *(const uint4*)&Kh[(size_t)(64 + strow) * 64 + stcol];
  vreg = *(const uint4*)&Vh[(size_t)strow * 2048 + 64 + stcol];
  __syncthreads();

  int cur = 0;
  for (int kt = 0; kt < 32; ++kt) {
    const ushort* Kc = &Ks[cur][0];
    const ushort* Vc = &Vs[cur][0];
    // QK^T swapped: sacc[n] lane(c,g) reg r = S[q=wid*16+c][k=n*16+g*4+r]
    f32x4 sacc[4];
#pragma unroll
    for (int n = 0; n < 4; ++n) sacc[n] = (f32x4){0.f, 0.f, 0.f, 0.f};
    __builtin_amdgcn_s_setprio(1);
#pragma unroll
    for (int kk = 0; kk < 2; ++kk)
#pragma unroll
      for (int n = 0; n < 4; ++n) {
        bf16x8 kf = *(const bf16x8*)&Kc[kidx[n][kk]];
        sacc[n] = __builtin_amdgcn_mfma_f32_16x16x32_bf16(kf, qf[kk], sacc[n], 0, 0, 0);
      }
    __builtin_amdgcn_s_setprio(0);
    // in-lane row max (16 values, one q-row) + 2 cross-g shuffles
    float mx0 = fmaxf(fmaxf(sacc[0][0], sacc[0][1]), fmaxf(sacc[0][2], sacc[0][3]));
    float mx1 = fmaxf(fmaxf(sacc[1][0], sacc[1][1]), fmaxf(sacc[1][2], sacc[1][3]));
    float mx2 = fmaxf(fmaxf(sacc[2][0], sacc[2][1]), fmaxf(sacc[2][2], sacc[2][3]));
    float mx3 = fmaxf(fmaxf(sacc[3][0], sacc[3][1]), fmaxf(sacc[3][2], sacc[3][3]));
    float mx = fmaxf(fmaxf(mx0, mx1), fmaxf(mx2, mx3));
    mx = fmaxf(mx, __shfl_xor(mx, 16));
    mx = fmaxf(mx, __shfl_xor(mx, 32));
    // defer-max: rescale only when the running max grew past THR=12 (log2)
    if (!__all(mx <= mrow + 12.0f)) {
      float mo = mrow;
      float mn = fmaxf(mo, mx);
      float corr = EXP2F(mo - mn);  // corr for q = c
      mrow = mn;
      lpart *= corr;
#pragma unroll
      for (int r = 0; r < 4; ++r) {  // oacc rows are q = g*4+r -> redistribute
        float cr = __shfl(corr, (g << 2) + r);
        oacc[0][r] *= cr; oacc[1][r] *= cr; oacc[2][r] *= cr; oacc[3][r] *= cr;
      }
    }
    const float mu = mrow;
    float p[4][4];
#pragma unroll
    for (int n = 0; n < 4; ++n)
#pragma unroll
      for (int r = 0; r < 4; ++r) p[n][r] = EXP2F(sacc[n][r] - mu);
    lpart += ((p[0][0] + p[0][1]) + (p[0][2] + p[0][3])) +
             ((p[1][0] + p[1][1]) + (p[1][2] + p[1][3])) +
             ((p[2][0] + p[2][1]) + (p[2][2] + p[2][3])) +
             ((p[3][0] + p[3][1]) + (p[3][2] + p[3][3]));
    // pack to bf16 pairs and store own-row P (4x ds_write_b64, 2-way banks)
#pragma unroll
    for (int n = 0; n < 4; ++n) {
      uint2 w;
      w.x = cvtpk(p[n][0], p[n][1]);
      w.y = cvtpk(p[n][2], p[n][3]);
      *(uint2*)&Ps[psw[n]] = w;
    }
    // PV: A-frag = own-row P (2x ds_read_b128), B-frag = Vt rows
    __builtin_amdgcn_s_setprio(1);
#pragma unroll
    for (int kk = 0; kk < 2; ++kk) {
      bf16x8 pa = *(const bf16x8*)&Ps[prd[kk]];
#pragma unroll
      for (int nd = 0; nd < 4; ++nd) {
        bf16x8 vf = *(const bf16x8*)&Vc[kidx[nd][kk]];
        oacc[nd] = __builtin_amdgcn_mfma_f32_16x16x32_bf16(pa, vf, oacc[nd], 0, 0, 0);
      }
    }
    __builtin_amdgcn_s_setprio(0);
    // stage prefetched tile kt+1 into the other buffer, then prefetch kt+2
    if (kt < 31) {
      *(uint4*)&Ks[cur ^ 1][stoff] = kreg;
      *(uint4*)&Vs[cur ^ 1][stoff] = vreg;
      if (kt < 30) {
        kreg = *(const uint4*)&Kh[(size_t)((kt + 2) * 64 + strow) * 64 + stcol];
        vreg = *(const uint4*)&Vh[(size_t)strow * 2048 + (kt + 2) * 64 + stcol];
      }
    }
    __syncthreads();
    cur ^= 1;
  }

  const int b = bh >> 4, h = bh & 15;
  lpart += __shfl_xor(lpart, 16);
  lpart += __shfl_xor(lpart, 32);
  float inv = 1.0f / lpart;  // for q = c
  float invr[4];
#pragma unroll
  for (int r = 0; r < 4; ++r) invr[r] = __shfl(inv, (g << 2) + r);
#pragma unroll
  for (int nd = 0; nd < 4; ++nd) {
    int d = nd * 16 + c;
#pragma unroll
    for (int r = 0; r < 4; ++r) {
      int s = qt * 128 + wid * 16 + (g << 2) + r;
      AO[(size_t)((b * 2048 + s) * 16 + h) * 64 + d] = f2bf(oacc[nd][r] * invr[r]);
    }
  }
}

extern "C" void kernel_launch(void* const* d_in, const int* in_sizes, int n_in,
                              void* d_out, int out_size, void* d_ws, size_t ws_size,
                              hipStream_t stream) {
  const float* x = (const float*)d_in[0];
  const float* w_qkv = (const float*)d_in[1];
  const float* b_qkv = (const float*)d_in[2];
  const float* w_out = (const float*)d_in[3];
  const float* b_out = (const float*)d_in[4];
  float* out = (float*)d_out;

  char* p = (char*)d_ws;
  ushort* xb = (ushort*)p;    p += (size_t)4096 * 1024 * 2;   // reused as AO later
  ushort* wqkvT = (ushort*)p; p += (size_t)3072 * 1024 * 2;
  ushort* woutT = (ushort*)p; p += (size_t)1024 * 1024 * 2;
  ushort* Qb = (ushort*)p;    p += (size_t)32 * 2048 * 64 * 2;
  ushort* Kb = (ushort*)p;    p += (size_t)32 * 2048 * 64 * 2;
  ushort* Vb = (ushort*)p;    p += (size_t)32 * 2048 * 64 * 2;
  ushort* Vtb = (ushort*)p;   p += (size_t)32 * 2048 * 64 * 2;
  ushort* AO = xb;  // xb dead after QKV GEMM; reuse (stream-ordered, safe)

  k_cast_bf16<<<2048, 256, 0, stream>>>(x, xb);
  k_transpose_cast<<<dim3(96, 32), 256, 0, stream>>>(w_qkv, wqkvT, 1024, 3072);
  k_transpose_cast<<<dim3(32, 32), 256, 0, stream>>>(w_out, woutT, 1024, 1024);
  k_gemm<0><<<dim3(24, 32), 256, 0, stream>>>(xb, wqkvT, b_qkv, Qb, Kb, Vb, nullptr);
  k_vtrans<<<dim3(32, 32), 256, 0, stream>>>(Vb, Vtb);
  k_attn<<<dim3(16, 32), 512, 0, stream>>>(Qb, Kb, Vtb, AO);
  k_gemm<1><<<dim3(8, 32), 256, 0, stream>>>(AO, woutT, b_out, nullptr, nullptr, nullptr, out);
}

// Round 9
// 130.363 us; speedup vs baseline: 4.0690x; 1.0322x over previous
//
#include <hip/hip_runtime.h>
#include <stdint.h>

typedef short bf16x8 __attribute__((ext_vector_type(8)));
typedef float f32x4 __attribute__((ext_vector_type(4)));

#if __has_builtin(__builtin_amdgcn_exp2f)
#define EXP2F(x) __builtin_amdgcn_exp2f(x)
#else
#define EXP2F(x) exp2f(x)
#endif

// 0.125 (1/sqrt(64)) * log2(e): folded into Q so QK^T scores come out in
// log2 domain directly (softmax uses native v_exp_f32 = exp2).
#define QSCALE 0.18033688011112042f

__device__ __forceinline__ unsigned short f2bf(float f) {
  unsigned u = __float_as_uint(f);
  u += 0x7fffu + ((u >> 16) & 1u);
  return (unsigned short)(u >> 16);
}

// pack 2 fp32 -> 2 bf16 in one dword (RNE), single VALU op
__device__ __forceinline__ unsigned cvtpk(float lo, float hi) {
  unsigned r;
  asm("v_cvt_pk_bf16_f32 %0, %1, %2" : "=v"(r) : "v"(lo), "v"(hi));
  return r;
}

// gfx950 cross-lane swaps (VALU pipe, not DS):
// pl32: a' = [a_lo|b_lo], b' = [a_hi|b_hi]  (32-lane halves)
// pl16: a' = [a0,b0,a2,b2], b' = [a1,b1,a3,b3] (16-lane groups g0..g3)
__device__ __forceinline__ void pl32(unsigned& a, unsigned& b) {
  asm("v_permlane32_swap_b32 %0, %1" : "+v"(a), "+v"(b));
}
__device__ __forceinline__ void pl16(unsigned& a, unsigned& b) {
  asm("v_permlane16_swap_b32 %0, %1" : "+v"(a), "+v"(b));
}

// async global->LDS, 16B per lane; LDS dest = waveBase + lane*16 (call sites
// pass &buf[t*8], t = wid*64+lane -> consistent).
__device__ __forceinline__ void gld16(const ushort* g, ushort* l) {
  __builtin_amdgcn_global_load_lds(
      (__attribute__((address_space(1))) void*)g,
      (__attribute__((address_space(3))) void*)l, 16, 0, 0);
}

// ---------------- prep kernels ----------------
__global__ __launch_bounds__(256) void k_cast_bf16(const float* __restrict__ in,
                                                   ushort* __restrict__ out) {
  int i = (blockIdx.x * 256 + threadIdx.x) * 8;
  float4 a = *(const float4*)(in + i);
  float4 b = *(const float4*)(in + i + 4);
  union { ushort u[8]; uint4 q; } r;
  r.u[0] = f2bf(a.x); r.u[1] = f2bf(a.y); r.u[2] = f2bf(a.z); r.u[3] = f2bf(a.w);
  r.u[4] = f2bf(b.x); r.u[5] = f2bf(b.y); r.u[6] = f2bf(b.z); r.u[7] = f2bf(b.w);
  *(uint4*)(out + i) = r.q;
}

// fp32 [R][C] -> bf16 [C][R]
__global__ __launch_bounds__(256) void k_transpose_cast(const float* __restrict__ in,
                                                        ushort* __restrict__ out,
                                                        int R, int C) {
  __shared__ float tl[32][33];
  int t = threadIdx.x;
  {
    int r = t >> 3, c4 = (t & 7) * 4;
    float4 v = *(const float4*)(in + (size_t)(blockIdx.y * 32 + r) * C + blockIdx.x * 32 + c4);
    tl[r][c4] = v.x; tl[r][c4 + 1] = v.y; tl[r][c4 + 2] = v.z; tl[r][c4 + 3] = v.w;
  }
  __syncthreads();
  {
    int c = t >> 3, r4 = (t & 7) * 4;
    union { ushort u[4]; uint2 q; } o;
    o.u[0] = f2bf(tl[r4][c]);     o.u[1] = f2bf(tl[r4 + 1][c]);
    o.u[2] = f2bf(tl[r4 + 2][c]); o.u[3] = f2bf(tl[r4 + 3][c]);
    *(uint2*)(out + (size_t)(blockIdx.x * 32 + c) * R + blockIdx.y * 32 + r4) = o.q;
  }
}

// V [bh][2048][64] -> Vt [bh][64][2048]
__global__ __launch_bounds__(256) void k_vtrans(const ushort* __restrict__ V,
                                                ushort* __restrict__ Vt) {
  __shared__ ushort tl[64 * 72];
  int t = threadIdx.x;
  const ushort* inp = V + (size_t)blockIdx.y * 131072 + blockIdx.x * 4096;
#pragma unroll
  for (int p = 0; p < 2; ++p) {
    int r = (t >> 3) + p * 32, c8 = (t & 7) * 8;
    *(uint4*)&tl[r * 72 + c8] = *(const uint4*)&inp[r * 64 + c8];
  }
  __syncthreads();
  ushort* outp = Vt + (size_t)blockIdx.y * 131072 + blockIdx.x * 64;
#pragma unroll
  for (int p = 0; p < 2; ++p) {
    int d = (t >> 3) + p * 32, s8 = (t & 7) * 8;
    union { ushort u[8]; uint4 q; } o;
#pragma unroll
    for (int j = 0; j < 8; ++j) o.u[j] = tl[(s8 + j) * 72 + d];
    *(uint4*)&outp[d * 2048 + s8] = o.q;
  }
}

// ---------------- GEMM: A[M][1024] bf16 x Bt[N][1024] bf16 ----------------
// m97-verified pattern: LINEAR LDS (no swizzle) + global_load_lds width 16.
// 128x128 tile, BK=32, 4 waves (2x2), each wave 64x64 (4x4 of 16x16 frags).
// MODE 0 epilogue scales the Q third by QSCALE (log2-domain softmax).
template <int MODE>
__global__ __launch_bounds__(256, 2) void k_gemm(
    const ushort* __restrict__ A, const ushort* __restrict__ Bt,
    const float* __restrict__ bias, ushort* __restrict__ Q,
    ushort* __restrict__ Ko, ushort* __restrict__ V, float* __restrict__ Out) {
  __shared__ ushort As[128 * 32];
  __shared__ ushort Bs[128 * 32];
  const int t = threadIdx.x;
  const int lane = t & 63, wid = t >> 6;
  const int wr = wid >> 1, wc = wid & 1;
  const int rt = blockIdx.y, ct = blockIdx.x;

  const int srow = t >> 2, sslot = t & 3;
  const ushort* ga = A + (size_t)(rt * 128 + srow) * 1024 + sslot * 8;
  const ushort* gb = Bt + (size_t)(ct * 128 + srow) * 1024 + sslot * 8;
  ushort* lA = &As[t * 8];
  ushort* lB = &Bs[t * 8];

  f32x4 acc[4][4];
#pragma unroll
  for (int m = 0; m < 4; ++m)
#pragma unroll
    for (int n = 0; n < 4; ++n) acc[m][n] = (f32x4){0.f, 0.f, 0.f, 0.f};

  int aidx[4], bidx[4];
#pragma unroll
  for (int m = 0; m < 4; ++m) {
    int ra = wr * 64 + m * 16 + (lane & 15);
    aidx[m] = ra * 32 + ((lane >> 4) << 3);
    int rb = wc * 64 + m * 16 + (lane & 15);
    bidx[m] = rb * 32 + ((lane >> 4) << 3);
  }

  gld16(ga, lA); gld16(ga + 65536, lA + 2048);
  gld16(gb, lB); gld16(gb + 65536, lB + 2048);

  for (int kt = 0; kt < 32; ++kt) {
    __syncthreads();
    bf16x8 af[4], bfv[4];
#pragma unroll
    for (int m = 0; m < 4; ++m) af[m] = *(const bf16x8*)&As[aidx[m]];
#pragma unroll
    for (int n = 0; n < 4; ++n) bfv[n] = *(const bf16x8*)&Bs[bidx[n]];
    __syncthreads();
    if (kt < 31) {
      const ushort* ga2 = ga + (kt + 1) * 32;
      const ushort* gb2 = gb + (kt + 1) * 32;
      gld16(ga2, lA); gld16(ga2 + 65536, lA + 2048);
      gld16(gb2, lB); gld16(gb2 + 65536, lB + 2048);
    }
#pragma unroll
    for (int m = 0; m < 4; ++m)
#pragma unroll
      for (int n = 0; n < 4; ++n)
        acc[m][n] = __builtin_amdgcn_mfma_f32_16x16x32_bf16(af[m], bfv[n], acc[m][n], 0, 0, 0);
  }

  const int colb = ct * 128 + wc * 64;
  const int rowb = rt * 128 + wr * 64;
  if constexpr (MODE == 0) {
#pragma unroll
    for (int n = 0; n < 4; ++n) {
      int col = colb + n * 16 + (lane & 15);
      float bv = bias[col];
      int three = col >> 10, hx = (col >> 6) & 15, d = col & 63;
      float sc = (three == 0) ? QSCALE : 1.0f;
      ushort* dst = (three == 0) ? Q : (three == 1) ? Ko : V;
#pragma unroll
      for (int m = 0; m < 4; ++m) {
        int r0 = rowb + m * 16 + ((lane >> 4) << 2);
#pragma unroll
        for (int r = 0; r < 4; ++r) {
          int row = r0 + r;
          int b = row >> 11, s = row & 2047;
          dst[(size_t)((b * 16 + hx) * 2048 + s) * 64 + d] = f2bf((acc[m][n][r] + bv) * sc);
        }
      }
    }
  } else {
#pragma unroll
    for (int n = 0; n < 4; ++n) {
      int col = colb + n * 16 + (lane & 15);
      float bv = bias[col];
#pragma unroll
      for (int m = 0; m < 4; ++m) {
        int r0 = rowb + m * 16 + ((lane >> 4) << 2);
#pragma unroll
        for (int r = 0; r < 4; ++r)
          Out[(size_t)(r0 + r) * 1024 + col] = acc[m][n][r] + bv;
      }
    }
  }
}

// ---------------- flash attention v3: LDS-traffic-minimized ----------------
// Diagnosis (r8 counters): LDS pipe ~90% busy (24 b128/tile/wave + 10.5M
// conflict cycles from the bank-aligned P buffer). Fix:
//  (1) P LDS round-trip -> v_permlane16/32_swap (VALU): per kk,
//      pl32+pl16 on W[2kk],W[2kk+1] (.x then .y) yields A-frag dwords
//      [D0,D1,D2,D3]; verified: k = 32kk+16h+8e+j maps exactly.
//  (2) 32 q-rows/wave (cb=0,1), 4 waves x 256 thr, QBLK=128: each K/V
//      frag ds_read feeds 2 MFMAs -> DS per q-row cut 2.4x total.
// grid (16,32) = 512 blocks = 2 blocks/CU x 4 waves = 8 waves/CU =
// 2 waves/SIMD -> VGPR up to 256 is free (no spill risk; launch_bounds
// (256,2) caps at 256; empirical: arg>=4 caps at 64 and spills).
// K/V double-buffered [2][64][72] reg-staged (+8 pad); staging write
// pattern (row=t>>2, col=(t&3)*16) is conflict-free per 16-lane phase.
__global__ __launch_bounds__(256, 2) void k_attn(const ushort* __restrict__ Qb,
                                                 const ushort* __restrict__ Kb,
                                                 const ushort* __restrict__ Vtb,
                                                 ushort* __restrict__ AO) {
  __shared__ ushort Ks[2][64 * 72];
  __shared__ ushort Vs[2][64 * 72];
  const int t = threadIdx.x, lane = t & 63, wid = t >> 6;  // wid 0..3
  const int c = lane & 15, g = lane >> 4;
  const int bh = blockIdx.y, qt = blockIdx.x;
  const ushort* Qh = Qb + (size_t)bh * 131072;
  const ushort* Kh = Kb + (size_t)bh * 131072;
  const ushort* Vh = Vtb + (size_t)bh * 131072;

  bf16x8 qf[2][2];
#pragma unroll
  for (int cb = 0; cb < 2; ++cb)
#pragma unroll
    for (int kk = 0; kk < 2; ++kk) {
      int row = qt * 128 + wid * 32 + cb * 16 + c;
      qf[cb][kk] = *(const bf16x8*)&Qh[row * 64 + kk * 32 + g * 8];
    }

  f32x4 oacc[2][4];
#pragma unroll
  for (int cb = 0; cb < 2; ++cb)
#pragma unroll
    for (int n = 0; n < 4; ++n) oacc[cb][n] = (f32x4){0.f, 0.f, 0.f, 0.f};
  float mrow[2] = {-1e30f, -1e30f}, lpart[2] = {0.f, 0.f};  // q = wid*32+cb*16+c

  // staging: 256 threads x 32B = one 64x64 bf16 tile each for K and V
  const int strow = t >> 2, stcol = (t & 3) * 16;
  const int stoff = strow * 72 + stcol;

  int kidx[4][2];
#pragma unroll
  for (int n = 0; n < 4; ++n)
#pragma unroll
    for (int kk = 0; kk < 2; ++kk)
      kidx[n][kk] = (n * 16 + c) * 72 + (kk * 4 + g) * 8;

  // prologue: tile 0 -> LDS buf0; tile 1 -> regs
  uint4 kr0 = *(const uint4*)&Kh[(size_t)strow * 64 + stcol];
  uint4 kr1 = *(const uint4*)&Kh[(size_t)strow * 64 + stcol + 8];
  uint4 vr0 = *(const uint4*)&Vh[(size_t)strow * 2048 + stcol];
  uint4 vr1 = *(const uint4*)&Vh[(size_t)strow * 2048 + stcol + 8];
  *(uint4*)&Ks[0][stoff] = kr0; *(uint4*)&Ks[0][stoff + 8] = kr1;
  *(uint4*)&Vs[0][stoff] = vr0; *(uint4*)&Vs[0][stoff + 8] = vr1;
  kr0 = *(const uint4*)&Kh[(size_t)(64 + strow) * 64 + stcol];
  kr1 = *(const uint4*)&Kh[(size_t)(64 + strow) * 64 + stcol + 8];
  vr0 = *(const uint4*)&Vh[(size_t)strow * 2048 + 64 + stcol];
  vr1 = *(const uint4*)&Vh[(size_t)strow * 2048 + 64 + stcol + 8];
  __syncthreads();

  int cur = 0;
  for (int kt = 0; kt < 32; ++kt) {
    const ushort* Kc = &Ks[cur][0];
    const ushort* Vc = &Vs[cur][0];
    // QK^T swapped: sacc[cb][n] lane(c,g) reg r = S[k=n*16+g*4+r][q=cb-row c]
    f32x4 sacc[2][4];
#pragma unroll
    for (int cb = 0; cb < 2; ++cb)
#pragma unroll
      for (int n = 0; n < 4; ++n) sacc[cb][n] = (f32x4){0.f, 0.f, 0.f, 0.f};
    __builtin_amdgcn_s_setprio(1);
#pragma unroll
    for (int kk = 0; kk < 2; ++kk)
#pragma unroll
      for (int n = 0; n < 4; ++n) {
        bf16x8 kf = *(const bf16x8*)&Kc[kidx[n][kk]];  // shared by both cb
        sacc[0][n] = __builtin_amdgcn_mfma_f32_16x16x32_bf16(kf, qf[0][kk], sacc[0][n], 0, 0, 0);
        sacc[1][n] = __builtin_amdgcn_mfma_f32_16x16x32_bf16(kf, qf[1][kk], sacc[1][n], 0, 0, 0);
      }
    __builtin_amdgcn_s_setprio(0);
    // softmax per cb: in-lane tree + 2 shfl; defer-max; P packed to W
    uint2 W[2][4];
#pragma unroll
    for (int cb = 0; cb < 2; ++cb) {
      float mx0 = fmaxf(fmaxf(sacc[cb][0][0], sacc[cb][0][1]), fmaxf(sacc[cb][0][2], sacc[cb][0][3]));
      float mx1 = fmaxf(fmaxf(sacc[cb][1][0], sacc[cb][1][1]), fmaxf(sacc[cb][1][2], sacc[cb][1][3]));
      float mx2 = fmaxf(fmaxf(sacc[cb][2][0], sacc[cb][2][1]), fmaxf(sacc[cb][2][2], sacc[cb][2][3]));
      float mx3 = fmaxf(fmaxf(sacc[cb][3][0], sacc[cb][3][1]), fmaxf(sacc[cb][3][2], sacc[cb][3][3]));
      float mx = fmaxf(fmaxf(mx0, mx1), fmaxf(mx2, mx3));
      mx = fmaxf(mx, __shfl_xor(mx, 16));
      mx = fmaxf(mx, __shfl_xor(mx, 32));
      if (!__all(mx <= mrow[cb] + 12.0f)) {
        float mo = mrow[cb];
        float mn = fmaxf(mo, mx);
        float corr = EXP2F(mo - mn);  // corr for q-row c
        mrow[cb] = mn;
        lpart[cb] *= corr;
#pragma unroll
        for (int r = 0; r < 4; ++r) {  // oacc rows are q = g*4+r
          float cr = __shfl(corr, (g << 2) + r);
          oacc[cb][0][r] *= cr; oacc[cb][1][r] *= cr;
          oacc[cb][2][r] *= cr; oacc[cb][3][r] *= cr;
        }
      }
      const float mu = mrow[cb];
      float ps = lpart[cb];
#pragma unroll
      for (int n = 0; n < 4; ++n) {
        float p0 = EXP2F(sacc[cb][n][0] - mu);
        float p1 = EXP2F(sacc[cb][n][1] - mu);
        float p2 = EXP2F(sacc[cb][n][2] - mu);
        float p3 = EXP2F(sacc[cb][n][3] - mu);
        ps += (p0 + p1) + (p2 + p3);
        W[cb][n].x = cvtpk(p0, p1);
        W[cb][n].y = cvtpk(p2, p3);
      }
      lpart[cb] = ps;
    }
    // PV: A-frags built in-register via permlane swaps; V-frags shared by cb
    __builtin_amdgcn_s_setprio(1);
#pragma unroll
    for (int kk = 0; kk < 2; ++kk) {
      bf16x8 paf[2];
#pragma unroll
      for (int cb = 0; cb < 2; ++cb) {
        unsigned a0 = W[cb][2 * kk].x, b0 = W[cb][2 * kk + 1].x;
        pl32(a0, b0); pl16(a0, b0);  // a0 = D0 (k+0,1), b0 = D2 (k+4,5)
        unsigned a1 = W[cb][2 * kk].y, b1 = W[cb][2 * kk + 1].y;
        pl32(a1, b1); pl16(a1, b1);  // a1 = D1 (k+2,3), b1 = D3 (k+6,7)
        union { unsigned u[4]; bf16x8 v; } fr;
        fr.u[0] = a0; fr.u[1] = a1; fr.u[2] = b0; fr.u[3] = b1;
        paf[cb] = fr.v;
      }
#pragma unroll
      for (int nd = 0; nd < 4; ++nd) {
        bf16x8 vf = *(const bf16x8*)&Vc[kidx[nd][kk]];
        oacc[0][nd] = __builtin_amdgcn_mfma_f32_16x16x32_bf16(paf[0], vf, oacc[0][nd], 0, 0, 0);
        oacc[1][nd] = __builtin_amdgcn_mfma_f32_16x16x32_bf16(paf[1], vf, oacc[1][nd], 0, 0, 0);
      }
    }
    __builtin_amdgcn_s_setprio(0);
    // stage prefetched tile kt+1 into the other buffer, then prefetch kt+2
    if (kt < 31) {
      ushort* kd = &Ks[cur ^ 1][stoff];
      *(uint4*)kd = kr0; *(uint4*)(kd + 8) = kr1;
      ushort* vd = &Vs[cur ^ 1][stoff];
      *(uint4*)vd = vr0; *(uint4*)(vd + 8) = vr1;
      if (kt < 30) {
        const ushort* gk = &Kh[(size_t)((kt + 2) * 64 + strow) * 64 + stcol];
        kr0 = *(const uint4*)gk; kr1 = *(const uint4*)(gk + 8);
        const ushort* gv = &Vh[(size_t)strow * 2048 + (kt + 2) * 64 + stcol];
        vr0 = *(const uint4*)gv; vr1 = *(const uint4*)(gv + 8);
      }
    }
    __syncthreads();
    cur ^= 1;
  }

  const int b = bh >> 4, h = bh & 15;
#pragma unroll
  for (int cb = 0; cb < 2; ++cb) {
    float lp = lpart[cb];
    lp += __shfl_xor(lp, 16);
    lp += __shfl_xor(lp, 32);
    float inv = 1.0f / lp;  // for q-row c of this cb
    float invr[4];
#pragma unroll
    for (int r = 0; r < 4; ++r) invr[r] = __shfl(inv, (g << 2) + r);
#pragma unroll
    for (int nd = 0; nd < 4; ++nd) {
      int d = nd * 16 + c;
#pragma unroll
      for (int r = 0; r < 4; ++r) {
        int s = qt * 128 + wid * 32 + cb * 16 + (g << 2) + r;
        AO[(size_t)((b * 2048 + s) * 16 + h) * 64 + d] = f2bf(oacc[cb][nd][r] * invr[r]);
      }
    }
  }
}

extern "C" void kernel_launch(void* const* d_in, const int* in_sizes, int n_in,
                              void* d_out, int out_size, void* d_ws, size_t ws_size,
                              hipStream_t stream) {
  const float* x = (const float*)d_in[0];
  const float* w_qkv = (const float*)d_in[1];
  const float* b_qkv = (const float*)d_in[2];
  const float* w_out = (const float*)d_in[3];
  const float* b_out = (const float*)d_in[4];
  float* out = (float*)d_out;

  char* p = (char*)d_ws;
  ushort* xb = (ushort*)p;    p += (size_t)4096 * 1024 * 2;   // reused as AO later
  ushort* wqkvT = (ushort*)p; p += (size_t)3072 * 1024 * 2;
  ushort* woutT = (ushort*)p; p += (size_t)1024 * 1024 * 2;
  ushort* Qb = (ushort*)p;    p += (size_t)32 * 2048 * 64 * 2;
  ushort* Kb = (ushort*)p;    p += (size_t)32 * 2048 * 64 * 2;
  ushort* Vb = (ushort*)p;    p += (size_t)32 * 2048 * 64 * 2;
  ushort* Vtb = (ushort*)p;   p += (size_t)32 * 2048 * 64 * 2;
  ushort* AO = xb;  // xb dead after QKV GEMM; reuse (stream-ordered, safe)

  k_cast_bf16<<<2048, 256, 0, stream>>>(x, xb);
  k_transpose_cast<<<dim3(96, 32), 256, 0, stream>>>(w_qkv, wqkvT, 1024, 3072);
  k_transpose_cast<<<dim3(32, 32), 256, 0, stream>>>(w_out, woutT, 1024, 1024);
  k_gemm<0><<<dim3(24, 32), 256, 0, stream>>>(xb, wqkvT, b_qkv, Qb, Kb, Vb, nullptr);
  k_vtrans<<<dim3(32, 32), 256, 0, stream>>>(Vb, Vtb);
  k_attn<<<dim3(16, 32), 256, 0, stream>>>(Qb, Kb, Vtb, AO);
  k_gemm<1><<<dim3(8, 32), 256, 0, stream>>>(AO, woutT, b_out, nullptr, nullptr, nullptr, out);
}